// Round 18
// baseline (125.896 us; speedup 1.0000x reference)
//
#include <hip/hip_runtime.h>
#include <hip/hip_bf16.h>
#include <stdint.h>

// Shapes (fixed by the problem)
#define B_  16
#define M_  2048            // T*N
#define C_  256
#define BM_ 32768           // B_*M_

typedef __bf16 bf16x8 __attribute__((ext_vector_type(8)));
typedef __bf16 bf16x2 __attribute__((ext_vector_type(2)));
typedef float  f32x4  __attribute__((ext_vector_type(4)));
typedef float  f32x16 __attribute__((ext_vector_type(16)));
typedef unsigned int uint2v __attribute__((ext_vector_type(2)));

__device__ __forceinline__ unsigned short f2bf(float f) {
    uint32_t u = __builtin_bit_cast(uint32_t, f);
    u += 0x7fffu + ((u >> 16) & 1u);          // RNE
    return (unsigned short)(u >> 16);
}

__device__ __forceinline__ uint32_t pkbf(float a, float b) {
    bf16x2 t; t[0] = (__bf16)a; t[1] = (__bf16)b;   // compiler -> v_cvt_pk_bf16_f32
    return __builtin_bit_cast(uint32_t, t);
}

__device__ __forceinline__ float bf2f(unsigned short u) {
    return __builtin_bit_cast(float, ((uint32_t)u) << 16);
}

// async global->LDS, 16B/lane; LDS dest = wave-uniform base, HW adds lane*16
__device__ __forceinline__ void gload16(const void* g, void* l) {
    __builtin_amdgcn_global_load_lds(
        (const __attribute__((address_space(1))) void*)g,
        (__attribute__((address_space(3))) void*)l, 16, 0, 0);
}

// Explicit LDS-DMA publish: drain vmcnt BEFORE the barrier, fence scheduler.
__device__ __forceinline__ void publish_barrier() {
    asm volatile("s_waitcnt vmcnt(0)" ::: "memory");
    __builtin_amdgcn_sched_barrier(0);
    __syncthreads();
    __builtin_amdgcn_sched_barrier(0);
}

// ---------------------------------------------------------------- kernel 1
// FUSED: blocks 0..8191 = l2norm; blocks 8192..8447 = weight prep.
__global__ void l2norm_prep_kernel(const float* __restrict__ x,
                                   unsigned short* __restrict__ nf,
                                   float* __restrict__ norms,
                                   const float* __restrict__ adj,
                                   const float* __restrict__ affw,
                                   unsigned short* __restrict__ adjT5,
                                   unsigned short* __restrict__ affwB) {
    if (blockIdx.x >= 8192) {                   // prep part
        int idx = (blockIdx.x - 8192) * 256 + threadIdx.x;
        int d = idx >> 8, c = idx & 255;
        adjT5[d * 256 + c] = f2bf(7.2134752f * adj[c * 256 + d]);
        affwB[idx] = f2bf(affw[idx]);
        return;
    }
    int w = threadIdx.x >> 6, lane = threadIdx.x & 63;
    int row = blockIdx.x * 4 + w;
    const float4 v = *reinterpret_cast<const float4*>(x + (size_t)row * 256 + lane * 4);
    float ss = v.x * v.x + v.y * v.y + v.z * v.z + v.w * v.w;
    #pragma unroll
    for (int m = 1; m < 64; m <<= 1) ss += __shfl_xor(ss, m);
    float nrm = sqrtf(ss);
    float s = 1.0f / fmaxf(nrm, 1e-12f);
    ushort4 o;
    o.x = f2bf(v.x * s); o.y = f2bf(v.y * s); o.z = f2bf(v.z * s); o.w = f2bf(v.w * s);
    *reinterpret_cast<ushort4*>(nf + (size_t)row * 256 + lane * 4) = o;
    if (lane == 0) norms[row] = nrm;
}

// ---------------------------------------------------------------- kernel 2
// One pass over nf producing Q (row-major), V3 (flash-staging-linear),
// K3 (flash-staging-linear) — r9 version verbatim.
__global__ __launch_bounds__(512, 2)
void dual_gemm(const unsigned short* __restrict__ A,
               const unsigned short* __restrict__ B1,
               const unsigned short* __restrict__ B2,
               const float* __restrict__ norms,
               const float* __restrict__ bias,
               unsigned short* __restrict__ outQ,
               unsigned short* __restrict__ outV3,
               unsigned short* __restrict__ outK3) {
    __shared__ unsigned short bb1[256 * 56];
    __shared__ unsigned short bb2[256 * 56];
    int tid = threadIdx.x;
    int w = tid >> 6, lane = tid & 63, g = lane >> 4, r = lane & 15;
    int m0 = blockIdx.x * 128;

    const f32x4 z = {0.f, 0.f, 0.f, 0.f};
    f32x4 accq[16], accv[16];
    #pragma unroll
    for (int i = 0; i < 16; i++) { accq[i] = z; accv[i] = z; }

    int row = m0 + w * 16 + r;
    int kvblk_r = row >> 5, mrow = row & 31;

    for (int dc = 0; dc < 8; dc++) {
        __syncthreads();
        #pragma unroll
        for (int it = 0; it < 2; it++) {
            int n = (w * 2 + it) * 16 + (lane >> 2);
            int t = lane & 3;
            *reinterpret_cast<uint4*>(&bb1[n * 56 + t * 8]) =
                *reinterpret_cast<const uint4*>(B1 + (size_t)n * 256 + dc * 32 + t * 8);
            *reinterpret_cast<uint4*>(&bb2[n * 56 + t * 8]) =
                *reinterpret_cast<const uint4*>(B2 + (size_t)n * 256 + dc * 32 + t * 8);
        }
        __syncthreads();
        bf16x8 af = *reinterpret_cast<const bf16x8*>(
            A + (size_t)row * 256 + dc * 32 + g * 8);
        // K3 store: c-range = dc*32+g*8 -> ch = dc*2+(g>>1), khl = g&1
        {
            int ch = dc * 2 + (g >> 1);
            int khl = g & 1;
            *reinterpret_cast<bf16x8*>(
                outK3 + (size_t)kvblk_r * 8192 + ch * 512 + (khl * 32 + mrow) * 8) = af;
        }
        #pragma unroll
        for (int nf16 = 0; nf16 < 16; nf16++) {
            bf16x8 b1f = *reinterpret_cast<const bf16x8*>(&bb1[(nf16 * 16 + r) * 56 + g * 8]);
            accq[nf16] = __builtin_amdgcn_mfma_f32_16x16x32_bf16(af, b1f, accq[nf16], 0, 0, 0);
            bf16x8 b2f = *reinterpret_cast<const bf16x8*>(&bb2[(nf16 * 16 + r) * 56 + g * 8]);
            accv[nf16] = __builtin_amdgcn_mfma_f32_16x16x32_bf16(af, b2f, accv[nf16], 0, 0, 0);
        }
    }
    // Q epilogue: row-major
    #pragma unroll
    for (int nf16 = 0; nf16 < 16; nf16++) {
        int n = nf16 * 16 + r;
        #pragma unroll
        for (int j = 0; j < 4; j++) {
            int m = m0 + w * 16 + g * 4 + j;
            outQ[(size_t)m * 256 + n] = f2bf(accq[nf16][j]);
        }
    }
    // V3 epilogue: staging-linear layout, * norms + bias
    int mm = m0 + w * 16 + g * 4;               // kv row of acc elem 0 (4-aligned)
    int kvblk = mm >> 5;
    int kv0 = mm & 31;
    int jj  = kv0 >> 4;                         // 16-kv half
    int hl2 = (kv0 >> 3) & 1;                   // 8-kv sub
    int e0  = kv0 & 7;                          // 0 or 4
    float4 nr = *reinterpret_cast<const float4*>(norms + mm);
    #pragma unroll
    for (int nf16 = 0; nf16 < 16; nf16++) {
        int n = nf16 * 16 + r;
        int cb = n >> 5, mr2 = n & 31;
        int slot = (cb * 2 + jj) * 64 + hl2 * 32 + mr2;
        float bv = bias[n];
        ushort4 o;
        o.x = f2bf(accv[nf16][0] * nr.x + bv);
        o.y = f2bf(accv[nf16][1] * nr.y + bv);
        o.z = f2bf(accv[nf16][2] * nr.z + bv);
        o.w = f2bf(accv[nf16][3] * nr.w + bv);
        *reinterpret_cast<ushort4*>(outV3 + (size_t)kvblk * 8192 + slot * 8 + e0) = o;
    }
}

// ---------------------------------------------------------------- kernel 3
// Flash v18 = r17 fused PV/QK interleave + split-lsum (two alternating
// accumulators break the 16-deep serial add chain in softmax; combined
// once in the epilogue). Sync structure identical to r17/r15.
// LDS 80KB: K0@0 K1@16K V0@32K V1@48K V2@64K; 2 blocks/CU = 160KB exactly.
__global__ __launch_bounds__(256, 2)
void flash_kernel(const unsigned short* __restrict__ Q,
                  const unsigned short* __restrict__ K3,
                  const unsigned short* __restrict__ V3,
                  float* __restrict__ out,
                  unsigned short* __restrict__ part0,
                  unsigned short* __restrict__ part1,
                  float* __restrict__ ml,
                  int h0bf16) {
    __shared__ __align__(16) char smem[81920];
    const int tid = threadIdx.x;
    const int w = tid >> 6, lane = tid & 63;
    const int hl = lane >> 5, m = lane & 31;    // lane half, lane-in-half
    const int blk = blockIdx.x;
    const int idx = blk >> 3;                   // 0..63
    const int b = (blk & 7) * 2 + (idx >> 5);   // XCD-pinned batch
    const int sub = idx & 31;
    const int mblk = sub >> 1, h = sub & 1;     // q-tile, kv half
    const int q0 = b * M_ + mblk * 128 + w * 32;

    // Q fragments: B-operand; lane holds Q[q0+m][ch*16 + hl*8 ..+8]
    bf16x8 qf[16];
    #pragma unroll
    for (int ch = 0; ch < 16; ch++)
        qf[ch] = *reinterpret_cast<const bf16x8*>(
            Q + (size_t)(q0 + m) * 256 + ch * 16 + hl * 8);

    const f32x16 z16 = {0,0,0,0, 0,0,0,0, 0,0,0,0, 0,0,0,0};
    f32x16 acc[8];
    #pragma unroll
    for (int cb = 0; cb < 8; cb++) acc[cb] = z16;
    float lsA = 0.0f, lsB = 0.0f;               // exp2 domain, fixed max = 0

    // staging sources: fully linear; per-thread base, +8192 ushorts/step
    const unsigned short* Ksrc =
        K3 + ((size_t)(b * 64 + h * 32) * 1024 + tid) * 8;
    const unsigned short* Vsrc =
        V3 + ((size_t)(b * 64 + h * 32) * 1024 + tid) * 8;

    auto stageK = [&](int step, int buf) {
        char* kb = smem + buf * 16384;
        const unsigned short* src = Ksrc + (size_t)step * 8192;
        #pragma unroll
        for (int it = 0; it < 4; it++)
            gload16(src + it * 2048, kb + (it * 256 + w * 64) * 16);
    };
    auto stageV = [&](int step, int buf) {
        char* vb = smem + 32768 + buf * 16384;
        const unsigned short* src = Vsrc + (size_t)step * 8192;
        #pragma unroll
        for (int it = 0; it < 4; it++)
            gload16(src + it * 2048, vb + (it * 256 + w * 64) * 16);
    };

    bf16x8 pf0, pf1;                            // P^T frags, carried across barrier
    // softmax+pack: sf -> pf0/pf1 (fixed max = 0, exp2 domain, split lsum)
    auto smpack = [&](f32x16& sf) {
        #pragma unroll
        for (int i = 0; i < 16; i += 2) {
            sf[i]     = exp2f(sf[i]);
            sf[i + 1] = exp2f(sf[i + 1]);
            lsA += sf[i];
            lsB += sf[i + 1];
        }
        uint32_t pk0 = pkbf(sf[0], sf[1]),   pk1 = pkbf(sf[2], sf[3]);
        uint32_t pk2 = pkbf(sf[4], sf[5]),   pk3 = pkbf(sf[6], sf[7]);
        uint32_t pk4 = pkbf(sf[8], sf[9]),   pk5 = pkbf(sf[10], sf[11]);
        uint32_t pk6 = pkbf(sf[12], sf[13]), pk7 = pkbf(sf[14], sf[15]);
        uint2v r0 = __builtin_amdgcn_permlane32_swap(pk0, pk2, false, false);
        uint2v r1 = __builtin_amdgcn_permlane32_swap(pk1, pk3, false, false);
        uint2v r2 = __builtin_amdgcn_permlane32_swap(pk4, pk6, false, false);
        uint2v r3 = __builtin_amdgcn_permlane32_swap(pk5, pk7, false, false);
        uint4 u0; u0.x = r0[0]; u0.y = r1[0]; u0.z = r0[1]; u0.w = r1[1];
        uint4 u1; u1.x = r2[0]; u1.y = r3[0]; u1.z = r2[1]; u1.w = r3[1];
        pf0 = __builtin_bit_cast(bf16x8, u0);   // P^T[kv 0..15][q]
        pf1 = __builtin_bit_cast(bf16x8, u1);   // P^T[kv 16..31][q]
    };

    stageK(0, 0); stageV(0, 0);
    publish_barrier();                          // K0,V0 ready
    stageK(1, 1); stageV(1, 1);
    {                                           // QK(0)+SM(0) reads K0
        const char* kbl = smem + lane * 16;
        f32x16 sf = z16;
        __builtin_amdgcn_s_setprio(1);
        #pragma unroll
        for (int ch = 0; ch < 16; ch++) {
            bf16x8 kf = *reinterpret_cast<const bf16x8*>(kbl + ch * 1024);
            sf = __builtin_amdgcn_mfma_f32_32x32x16_bf16(kf, qf[ch], sf, 0, 0, 0);
        }
        __builtin_amdgcn_s_setprio(0);
        smpack(sf);
    }

    int vcur = 0;                               // V buffer of step s
    for (int s = 0; s < 32; s++) {
        publish_barrier();                      // publishes stage(s+1)
        if (s + 2 < 32) {
            int vst = vcur + 2; if (vst >= 3) vst -= 3;
            stageK(s + 2, s & 1);               // K[s&1]: QK(s) done pre-barrier
            stageV(s + 2, vst);                 // V[(s+2)%3]: PV(s-1) done pre-barrier
        }
        const char* vbl = smem + 32768 + vcur * 16384 + lane * 16;
        bf16x8 p0 = pf0, p1 = pf1;
        if (s + 1 < 32) {
            // ---- fused: PV(s) interleaved 1:1 with QK(s+1)
            const char* kbl = smem + ((s + 1) & 1) * 16384 + lane * 16;
            f32x16 sf = z16;
            __builtin_amdgcn_s_setprio(1);
            #pragma unroll
            for (int i = 0; i < 16; i++) {
                bf16x8 vf = *reinterpret_cast<const bf16x8*>(vbl + i * 1024);
                acc[i >> 1] = __builtin_amdgcn_mfma_f32_32x32x16_bf16(
                    vf, (i & 1) ? p1 : p0, acc[i >> 1], 0, 0, 0);
                bf16x8 kf = *reinterpret_cast<const bf16x8*>(kbl + i * 1024);
                sf = __builtin_amdgcn_mfma_f32_32x32x16_bf16(kf, qf[i], sf, 0, 0, 0);
            }
            __builtin_amdgcn_s_setprio(0);
            smpack(sf);                         // SM(s+1) -> pf0/pf1
        } else {
            // ---- tail: PV(31) only
            __builtin_amdgcn_s_setprio(1);
            #pragma unroll
            for (int i = 0; i < 16; i++) {
                bf16x8 vf = *reinterpret_cast<const bf16x8*>(vbl + i * 1024);
                acc[i >> 1] = __builtin_amdgcn_mfma_f32_32x32x16_bf16(
                    vf, (i & 1) ? p1 : p0, acc[i >> 1], 0, 0, 0);
            }
            __builtin_amdgcn_s_setprio(0);
        }
        vcur++; if (vcur >= 3) vcur -= 3;
    }

    // ---- epilogue: per-q-row lsum, write normalized bf16 partial + weight
    float lsum = lsA + lsB;
    lsum += __shfl_xor(lsum, 32);
    float inv = 1.0f / lsum;
    size_t qrow = (size_t)(q0 + m);
    if (h0bf16 || h == 1) {
        unsigned short* myp = h ? part1 : part0;
        #pragma unroll
        for (int cb = 0; cb < 8; cb++)
            #pragma unroll
            for (int q4 = 0; q4 < 4; q4++) {
                int c0i = cb * 32 + q4 * 8 + 4 * hl;
                uint2 u;
                u.x = pkbf(acc[cb][q4 * 4 + 0] * inv, acc[cb][q4 * 4 + 1] * inv);
                u.y = pkbf(acc[cb][q4 * 4 + 2] * inv, acc[cb][q4 * 4 + 3] * inv);
                *reinterpret_cast<uint2*>(myp + qrow * 256 + c0i) = u;
            }
    } else {
        #pragma unroll
        for (int cb = 0; cb < 8; cb++)
            #pragma unroll
            for (int q4 = 0; q4 < 4; q4++) {
                int c0i = cb * 32 + q4 * 8 + 4 * hl;
                float4 o;
                o.x = acc[cb][q4 * 4 + 0] * inv;
                o.y = acc[cb][q4 * 4 + 1] * inv;
                o.z = acc[cb][q4 * 4 + 2] * inv;
                o.w = acc[cb][q4 * 4 + 3] * inv;
                *reinterpret_cast<float4*>(out + qrow * 256 + c0i) = o;
            }
    }
    if (hl == 0) ml[h * BM_ + qrow] = lsum;
}

// ---------------------------------------------------------------- kernel 4
// Merge halves (exact weighted combine) + LayerNorm + LeakyReLU.
// 2048 blocks x 4-row loop (G11 grid sizing; 4x fewer dispatch rounds).
// XCD-pinned: xcd = blk&7 reads the partials its own XCD's flash wrote.
__global__ void merge_ln_kernel(const unsigned short* __restrict__ part0,
                                const unsigned short* __restrict__ part1,
                                const float* __restrict__ ml,
                                const float* __restrict__ gam,
                                const float* __restrict__ bet,
                                float* __restrict__ out,
                                int h0bf16) {
    int w = threadIdx.x >> 6, lane = threadIdx.x & 63;
    int xcd = blockIdx.x & 7, j = blockIdx.x >> 3;   // j: 0..255
    size_t base = (size_t)xcd * 4096 + (size_t)j * 16;  // rows of batches {2x,2x+1}
    float4 gg = *reinterpret_cast<const float4*>(gam + lane * 4);
    float4 bb = *reinterpret_cast<const float4*>(bet + lane * 4);
    #pragma unroll
    for (int it = 0; it < 4; it++) {
        size_t row = base + it * 4 + w;
        float w0 = ml[row], w1 = ml[BM_ + row];
        float rs = 1.0f / (w0 + w1);
        float a0 = w0 * rs, a1 = w1 * rs;
        float4 v;
        ushort4 p1 = *reinterpret_cast<const ushort4*>(part1 + row * 256 + lane * 4);
        if (h0bf16) {
            ushort4 p0 = *reinterpret_cast<const ushort4*>(part0 + row * 256 + lane * 4);
            v.x = a0 * bf2f(p0.x) + a1 * bf2f(p1.x);
            v.y = a0 * bf2f(p0.y) + a1 * bf2f(p1.y);
            v.z = a0 * bf2f(p0.z) + a1 * bf2f(p1.z);
            v.w = a0 * bf2f(p0.w) + a1 * bf2f(p1.w);
        } else {
            float4 o0 = *reinterpret_cast<float4*>(out + row * 256 + lane * 4);
            v.x = a0 * o0.x + a1 * bf2f(p1.x);
            v.y = a0 * o0.y + a1 * bf2f(p1.y);
            v.z = a0 * o0.z + a1 * bf2f(p1.z);
            v.w = a0 * o0.w + a1 * bf2f(p1.w);
        }
        float s = v.x + v.y + v.z + v.w;
        float q = v.x * v.x + v.y * v.y + v.z * v.z + v.w * v.w;
        #pragma unroll
        for (int mm = 1; mm < 64; mm <<= 1) { s += __shfl_xor(s, mm); q += __shfl_xor(q, mm); }
        float mu = s * (1.0f / 256.0f);
        float var = q * (1.0f / 256.0f) - mu * mu;
        float rstd = rsqrtf(var + 1e-5f);
        float4 o;
        o.x = (v.x - mu) * rstd * gg.x + bb.x;
        o.y = (v.y - mu) * rstd * gg.y + bb.y;
        o.z = (v.z - mu) * rstd * gg.z + bb.z;
        o.w = (v.w - mu) * rstd * gg.w + bb.w;
        o.x = o.x >= 0.f ? o.x : 0.01f * o.x;
        o.y = o.y >= 0.f ? o.y : 0.01f * o.y;
        o.z = o.z >= 0.f ? o.z : 0.01f * o.z;
        o.w = o.w >= 0.f ? o.w : 0.01f * o.w;
        *reinterpret_cast<float4*>(out + row * 256 + lane * 4) = o;
    }
}

// ---------------------------------------------------------------- launcher
extern "C" void kernel_launch(void* const* d_in, const int* in_sizes, int n_in,
                              void* d_out, int out_size, void* d_ws, size_t ws_size,
                              hipStream_t stream) {
    const float* local_feat = (const float*)d_in[0];
    const float* adj_w    = (const float*)d_in[3];
    const float* affine_w = (const float*)d_in[4];
    const float* affine_b = (const float*)d_in[5];
    const float* ln_g     = (const float*)d_in[6];
    const float* ln_b     = (const float*)d_in[7];
    float* out = (float*)d_out;

    char* ws = (char*)d_ws;
    unsigned short* nf    = (unsigned short*)(ws);                 // 16 MiB (dead after dual_gemm)
    unsigned short* q     = (unsigned short*)(ws + 16777216);      // 16 MiB
    unsigned short* v3    = (unsigned short*)(ws + 33554432);      // 16 MiB
    unsigned short* k3    = (unsigned short*)(ws + 50331648);      // 16 MiB -> 67108864
    unsigned short* part0 = (unsigned short*)(ws);                 // aliases nf (dead)
    unsigned short* part1;
    unsigned short* adjT5;
    unsigned short* affw;
    float*          norms;
    float*          ml;

    // primary layout high-water = 84,279,296 B (r12 proved >= 84,283,392 B)
    const size_t need = 84279296ull;
    int h0bf16 = (ws_size >= need) ? 1 : 0;
    if (h0bf16) {
        part1 = (unsigned short*)(ws + 67108864);  // 16 MiB -> 83886080
        adjT5 = (unsigned short*)(ws + 83886080);  // 128 KiB
        affw  = (unsigned short*)(ws + 84017152);  // 128 KiB
        norms = (float*)         (ws + 84148224);  // 128 KiB -> 84279296
        ml    = (float*)         (ws + 83886080);  // aliases adjT5+affw (dead)
    } else {
        part1 = (unsigned short*)(ws);             // aliases nf (part0 unused)
        adjT5 = (unsigned short*)(ws + 67108864);  // 128 KiB
        affw  = (unsigned short*)(ws + 67239936);  // 128 KiB
        norms = (float*)         (ws + 67371008);  // 128 KiB -> 67502080 (r9-proven)
        ml    = (float*)         (ws + 67108864);  // aliases adjT5+affw (dead)
    }

    l2norm_prep_kernel<<<8448, 256, 0, stream>>>(local_feat, nf, norms,
                                                 adj_w, affine_w, adjT5, affw);
    dual_gemm<<<BM_ / 128, 512, 0, stream>>>(nf, adjT5, affw, norms, affine_b, q, v3, k3);
    flash_kernel<<<512, 256, 0, stream>>>(q, k3, v3, out, part0, part1, ml, h0bf16);
    merge_ln_kernel<<<2048, 256, 0, stream>>>(part0, part1, ml, ln_g, ln_b, out, h0bf16);
}

// Round 19
// 123.103 us; speedup vs baseline: 1.0227x; 1.0227x over previous
//
#include <hip/hip_runtime.h>
#include <hip/hip_bf16.h>
#include <stdint.h>

// Shapes (fixed by the problem)
#define B_  16
#define M_  2048            // T*N
#define C_  256
#define BM_ 32768           // B_*M_

typedef __bf16 bf16x8 __attribute__((ext_vector_type(8)));
typedef __bf16 bf16x2 __attribute__((ext_vector_type(2)));
typedef float  f32x4  __attribute__((ext_vector_type(4)));
typedef float  f32x16 __attribute__((ext_vector_type(16)));
typedef unsigned int uint2v __attribute__((ext_vector_type(2)));

__device__ __forceinline__ unsigned short f2bf(float f) {
    uint32_t u = __builtin_bit_cast(uint32_t, f);
    u += 0x7fffu + ((u >> 16) & 1u);          // RNE
    return (unsigned short)(u >> 16);
}

__device__ __forceinline__ uint32_t pkbf(float a, float b) {
    bf16x2 t; t[0] = (__bf16)a; t[1] = (__bf16)b;   // compiler -> v_cvt_pk_bf16_f32
    return __builtin_bit_cast(uint32_t, t);
}

__device__ __forceinline__ float bf2f(unsigned short u) {
    return __builtin_bit_cast(float, ((uint32_t)u) << 16);
}

// async global->LDS, 16B/lane; LDS dest = wave-uniform base, HW adds lane*16
__device__ __forceinline__ void gload16(const void* g, void* l) {
    __builtin_amdgcn_global_load_lds(
        (const __attribute__((address_space(1))) void*)g,
        (__attribute__((address_space(3))) void*)l, 16, 0, 0);
}

// Explicit LDS-DMA publish: drain vmcnt BEFORE the barrier, fence scheduler.
__device__ __forceinline__ void publish_barrier() {
    asm volatile("s_waitcnt vmcnt(0)" ::: "memory");
    __builtin_amdgcn_sched_barrier(0);
    __syncthreads();
    __builtin_amdgcn_sched_barrier(0);
}

// ---------------------------------------------------------------- kernel 1
// FUSED: blocks 0..8191 = l2norm; blocks 8192..8447 = weight prep.
__global__ void l2norm_prep_kernel(const float* __restrict__ x,
                                   unsigned short* __restrict__ nf,
                                   float* __restrict__ norms,
                                   const float* __restrict__ adj,
                                   const float* __restrict__ affw,
                                   unsigned short* __restrict__ adjT5,
                                   unsigned short* __restrict__ affwB) {
    if (blockIdx.x >= 8192) {                   // prep part
        int idx = (blockIdx.x - 8192) * 256 + threadIdx.x;
        int d = idx >> 8, c = idx & 255;
        adjT5[d * 256 + c] = f2bf(7.2134752f * adj[c * 256 + d]);
        affwB[idx] = f2bf(affw[idx]);
        return;
    }
    int w = threadIdx.x >> 6, lane = threadIdx.x & 63;
    int row = blockIdx.x * 4 + w;
    const float4 v = *reinterpret_cast<const float4*>(x + (size_t)row * 256 + lane * 4);
    float ss = v.x * v.x + v.y * v.y + v.z * v.z + v.w * v.w;
    #pragma unroll
    for (int m = 1; m < 64; m <<= 1) ss += __shfl_xor(ss, m);
    float nrm = sqrtf(ss);
    float s = 1.0f / fmaxf(nrm, 1e-12f);
    ushort4 o;
    o.x = f2bf(v.x * s); o.y = f2bf(v.y * s); o.z = f2bf(v.z * s); o.w = f2bf(v.w * s);
    *reinterpret_cast<ushort4*>(nf + (size_t)row * 256 + lane * 4) = o;
    if (lane == 0) norms[row] = nrm;
}

// ---------------------------------------------------------------- kernel 2
// One pass over nf producing Q (row-major), V3 (flash-staging-linear),
// K3 (flash-staging-linear). (512,1): 128 AGPR acc + ~100 VGPR fits the
// 256-reg budget — the old (512,2) 128-reg cap against 128 AGPRs forced
// permanent scratch spill in the hot loop.
__global__ __launch_bounds__(512, 1)
void dual_gemm(const unsigned short* __restrict__ A,
               const unsigned short* __restrict__ B1,
               const unsigned short* __restrict__ B2,
               const float* __restrict__ norms,
               const float* __restrict__ bias,
               unsigned short* __restrict__ outQ,
               unsigned short* __restrict__ outV3,
               unsigned short* __restrict__ outK3) {
    __shared__ unsigned short bb1[256 * 56];
    __shared__ unsigned short bb2[256 * 56];
    int tid = threadIdx.x;
    int w = tid >> 6, lane = tid & 63, g = lane >> 4, r = lane & 15;
    int m0 = blockIdx.x * 128;

    const f32x4 z = {0.f, 0.f, 0.f, 0.f};
    f32x4 accq[16], accv[16];
    #pragma unroll
    for (int i = 0; i < 16; i++) { accq[i] = z; accv[i] = z; }

    int row = m0 + w * 16 + r;
    int kvblk_r = row >> 5, mrow = row & 31;

    for (int dc = 0; dc < 8; dc++) {
        __syncthreads();
        #pragma unroll
        for (int it = 0; it < 2; it++) {
            int n = (w * 2 + it) * 16 + (lane >> 2);
            int t = lane & 3;
            *reinterpret_cast<uint4*>(&bb1[n * 56 + t * 8]) =
                *reinterpret_cast<const uint4*>(B1 + (size_t)n * 256 + dc * 32 + t * 8);
            *reinterpret_cast<uint4*>(&bb2[n * 56 + t * 8]) =
                *reinterpret_cast<const uint4*>(B2 + (size_t)n * 256 + dc * 32 + t * 8);
        }
        __syncthreads();
        bf16x8 af = *reinterpret_cast<const bf16x8*>(
            A + (size_t)row * 256 + dc * 32 + g * 8);
        // K3 store: c-range = dc*32+g*8 -> ch = dc*2+(g>>1), khl = g&1
        {
            int ch = dc * 2 + (g >> 1);
            int khl = g & 1;
            *reinterpret_cast<bf16x8*>(
                outK3 + (size_t)kvblk_r * 8192 + ch * 512 + (khl * 32 + mrow) * 8) = af;
        }
        #pragma unroll
        for (int nf16 = 0; nf16 < 16; nf16++) {
            bf16x8 b1f = *reinterpret_cast<const bf16x8*>(&bb1[(nf16 * 16 + r) * 56 + g * 8]);
            accq[nf16] = __builtin_amdgcn_mfma_f32_16x16x32_bf16(af, b1f, accq[nf16], 0, 0, 0);
            bf16x8 b2f = *reinterpret_cast<const bf16x8*>(&bb2[(nf16 * 16 + r) * 56 + g * 8]);
            accv[nf16] = __builtin_amdgcn_mfma_f32_16x16x32_bf16(af, b2f, accv[nf16], 0, 0, 0);
        }
    }
    // Q epilogue: row-major
    #pragma unroll
    for (int nf16 = 0; nf16 < 16; nf16++) {
        int n = nf16 * 16 + r;
        #pragma unroll
        for (int j = 0; j < 4; j++) {
            int m = m0 + w * 16 + g * 4 + j;
            outQ[(size_t)m * 256 + n] = f2bf(accq[nf16][j]);
        }
    }
    // V3 epilogue: staging-linear layout, * norms + bias
    int mm = m0 + w * 16 + g * 4;               // kv row of acc elem 0 (4-aligned)
    int kvblk = mm >> 5;
    int kv0 = mm & 31;
    int jj  = kv0 >> 4;                         // 16-kv half
    int hl2 = (kv0 >> 3) & 1;                   // 8-kv sub
    int e0  = kv0 & 7;                          // 0 or 4
    float4 nr = *reinterpret_cast<const float4*>(norms + mm);
    #pragma unroll
    for (int nf16 = 0; nf16 < 16; nf16++) {
        int n = nf16 * 16 + r;
        int cb = n >> 5, mr2 = n & 31;
        int slot = (cb * 2 + jj) * 64 + hl2 * 32 + mr2;
        float bv = bias[n];
        ushort4 o;
        o.x = f2bf(accv[nf16][0] * nr.x + bv);
        o.y = f2bf(accv[nf16][1] * nr.y + bv);
        o.z = f2bf(accv[nf16][2] * nr.z + bv);
        o.w = f2bf(accv[nf16][3] * nr.w + bv);
        *reinterpret_cast<ushort4*>(outV3 + (size_t)kvblk * 8192 + slot * 8 + e0) = o;
    }
}

// ---------------------------------------------------------------- kernel 3
// Flash v17 (r17 verbatim — best measured): fused PV(s)/QK(s+1) 1:1
// interleave fills QK's serial-chain latency with PV's independent chains.
// LDS 80KB: K0@0 K1@16K V0@32K V1@48K V2@64K; 2 blocks/CU = 160KB exactly.
__global__ __launch_bounds__(256, 2)
void flash_kernel(const unsigned short* __restrict__ Q,
                  const unsigned short* __restrict__ K3,
                  const unsigned short* __restrict__ V3,
                  float* __restrict__ out,
                  unsigned short* __restrict__ part0,
                  unsigned short* __restrict__ part1,
                  float* __restrict__ ml,
                  int h0bf16) {
    __shared__ __align__(16) char smem[81920];
    const int tid = threadIdx.x;
    const int w = tid >> 6, lane = tid & 63;
    const int hl = lane >> 5, m = lane & 31;    // lane half, lane-in-half
    const int blk = blockIdx.x;
    const int idx = blk >> 3;                   // 0..63
    const int b = (blk & 7) * 2 + (idx >> 5);   // XCD-pinned batch
    const int sub = idx & 31;
    const int mblk = sub >> 1, h = sub & 1;     // q-tile, kv half
    const int q0 = b * M_ + mblk * 128 + w * 32;

    // Q fragments: B-operand; lane holds Q[q0+m][ch*16 + hl*8 ..+8]
    bf16x8 qf[16];
    #pragma unroll
    for (int ch = 0; ch < 16; ch++)
        qf[ch] = *reinterpret_cast<const bf16x8*>(
            Q + (size_t)(q0 + m) * 256 + ch * 16 + hl * 8);

    const f32x16 z16 = {0,0,0,0, 0,0,0,0, 0,0,0,0, 0,0,0,0};
    f32x16 acc[8];
    #pragma unroll
    for (int cb = 0; cb < 8; cb++) acc[cb] = z16;
    float lsum = 0.0f;                          // exp2 domain, fixed max = 0

    // staging sources: fully linear; per-thread base, +8192 ushorts/step
    const unsigned short* Ksrc =
        K3 + ((size_t)(b * 64 + h * 32) * 1024 + tid) * 8;
    const unsigned short* Vsrc =
        V3 + ((size_t)(b * 64 + h * 32) * 1024 + tid) * 8;

    auto stageK = [&](int step, int buf) {
        char* kb = smem + buf * 16384;
        const unsigned short* src = Ksrc + (size_t)step * 8192;
        #pragma unroll
        for (int it = 0; it < 4; it++)
            gload16(src + it * 2048, kb + (it * 256 + w * 64) * 16);
    };
    auto stageV = [&](int step, int buf) {
        char* vb = smem + 32768 + buf * 16384;
        const unsigned short* src = Vsrc + (size_t)step * 8192;
        #pragma unroll
        for (int it = 0; it < 4; it++)
            gload16(src + it * 2048, vb + (it * 256 + w * 64) * 16);
    };

    bf16x8 pf0, pf1;                            // P^T frags, carried across barrier
    // softmax+pack: sf -> pf0/pf1 (fixed max = 0, exp2 domain)
    auto smpack = [&](f32x16& sf) {
        #pragma unroll
        for (int i = 0; i < 16; i++) {
            sf[i] = exp2f(sf[i]);
            lsum += sf[i];
        }
        uint32_t pk0 = pkbf(sf[0], sf[1]),   pk1 = pkbf(sf[2], sf[3]);
        uint32_t pk2 = pkbf(sf[4], sf[5]),   pk3 = pkbf(sf[6], sf[7]);
        uint32_t pk4 = pkbf(sf[8], sf[9]),   pk5 = pkbf(sf[10], sf[11]);
        uint32_t pk6 = pkbf(sf[12], sf[13]), pk7 = pkbf(sf[14], sf[15]);
        uint2v r0 = __builtin_amdgcn_permlane32_swap(pk0, pk2, false, false);
        uint2v r1 = __builtin_amdgcn_permlane32_swap(pk1, pk3, false, false);
        uint2v r2 = __builtin_amdgcn_permlane32_swap(pk4, pk6, false, false);
        uint2v r3 = __builtin_amdgcn_permlane32_swap(pk5, pk7, false, false);
        uint4 u0; u0.x = r0[0]; u0.y = r1[0]; u0.z = r0[1]; u0.w = r1[1];
        uint4 u1; u1.x = r2[0]; u1.y = r3[0]; u1.z = r2[1]; u1.w = r3[1];
        pf0 = __builtin_bit_cast(bf16x8, u0);   // P^T[kv 0..15][q]
        pf1 = __builtin_bit_cast(bf16x8, u1);   // P^T[kv 16..31][q]
    };

    stageK(0, 0); stageV(0, 0);
    publish_barrier();                          // K0,V0 ready
    stageK(1, 1); stageV(1, 1);
    {                                           // QK(0)+SM(0) reads K0
        const char* kbl = smem + lane * 16;
        f32x16 sf = z16;
        __builtin_amdgcn_s_setprio(1);
        #pragma unroll
        for (int ch = 0; ch < 16; ch++) {
            bf16x8 kf = *reinterpret_cast<const bf16x8*>(kbl + ch * 1024);
            sf = __builtin_amdgcn_mfma_f32_32x32x16_bf16(kf, qf[ch], sf, 0, 0, 0);
        }
        __builtin_amdgcn_s_setprio(0);
        smpack(sf);
    }

    int vcur = 0;                               // V buffer of step s
    for (int s = 0; s < 32; s++) {
        publish_barrier();                      // publishes stage(s+1)
        if (s + 2 < 32) {
            int vst = vcur + 2; if (vst >= 3) vst -= 3;
            stageK(s + 2, s & 1);               // K[s&1]: QK(s) done pre-barrier
            stageV(s + 2, vst);                 // V[(s+2)%3]: PV(s-1) done pre-barrier
        }
        const char* vbl = smem + 32768 + vcur * 16384 + lane * 16;
        bf16x8 p0 = pf0, p1 = pf1;
        if (s + 1 < 32) {
            // ---- fused: PV(s) interleaved 1:1 with QK(s+1)
            const char* kbl = smem + ((s + 1) & 1) * 16384 + lane * 16;
            f32x16 sf = z16;
            __builtin_amdgcn_s_setprio(1);
            #pragma unroll
            for (int i = 0; i < 16; i++) {
                bf16x8 vf = *reinterpret_cast<const bf16x8*>(vbl + i * 1024);
                acc[i >> 1] = __builtin_amdgcn_mfma_f32_32x32x16_bf16(
                    vf, (i & 1) ? p1 : p0, acc[i >> 1], 0, 0, 0);
                bf16x8 kf = *reinterpret_cast<const bf16x8*>(kbl + i * 1024);
                sf = __builtin_amdgcn_mfma_f32_32x32x16_bf16(kf, qf[i], sf, 0, 0, 0);
            }
            __builtin_amdgcn_s_setprio(0);
            smpack(sf);                         // SM(s+1) -> pf0/pf1
        } else {
            // ---- tail: PV(31) only
            __builtin_amdgcn_s_setprio(1);
            #pragma unroll
            for (int i = 0; i < 16; i++) {
                bf16x8 vf = *reinterpret_cast<const bf16x8*>(vbl + i * 1024);
                acc[i >> 1] = __builtin_amdgcn_mfma_f32_32x32x16_bf16(
                    vf, (i & 1) ? p1 : p0, acc[i >> 1], 0, 0, 0);
            }
            __builtin_amdgcn_s_setprio(0);
        }
        vcur++; if (vcur >= 3) vcur -= 3;
    }

    // ---- epilogue: per-q-row lsum, write normalized bf16 partial + weight
    lsum += __shfl_xor(lsum, 32);
    float inv = 1.0f / lsum;
    size_t qrow = (size_t)(q0 + m);
    if (h0bf16 || h == 1) {
        unsigned short* myp = h ? part1 : part0;
        #pragma unroll
        for (int cb = 0; cb < 8; cb++)
            #pragma unroll
            for (int q4 = 0; q4 < 4; q4++) {
                int c0i = cb * 32 + q4 * 8 + 4 * hl;
                uint2 u;
                u.x = pkbf(acc[cb][q4 * 4 + 0] * inv, acc[cb][q4 * 4 + 1] * inv);
                u.y = pkbf(acc[cb][q4 * 4 + 2] * inv, acc[cb][q4 * 4 + 3] * inv);
                *reinterpret_cast<uint2*>(myp + qrow * 256 + c0i) = u;
            }
    } else {
        #pragma unroll
        for (int cb = 0; cb < 8; cb++)
            #pragma unroll
            for (int q4 = 0; q4 < 4; q4++) {
                int c0i = cb * 32 + q4 * 8 + 4 * hl;
                float4 o;
                o.x = acc[cb][q4 * 4 + 0] * inv;
                o.y = acc[cb][q4 * 4 + 1] * inv;
                o.z = acc[cb][q4 * 4 + 2] * inv;
                o.w = acc[cb][q4 * 4 + 3] * inv;
                *reinterpret_cast<float4*>(out + qrow * 256 + c0i) = o;
            }
    }
    if (hl == 0) ml[h * BM_ + qrow] = lsum;
}

// ---------------------------------------------------------------- kernel 4
// Merge halves (exact weighted combine) + LayerNorm + LeakyReLU.
// XCD-pinned: block reads the partials its own XCD's flash blocks wrote.
__global__ void merge_ln_kernel(const unsigned short* __restrict__ part0,
                                const unsigned short* __restrict__ part1,
                                const float* __restrict__ ml,
                                const float* __restrict__ gam,
                                const float* __restrict__ bet,
                                float* __restrict__ out,
                                int h0bf16) {
    int w = threadIdx.x >> 6, lane = threadIdx.x & 63;
    int blk = blockIdx.x;                       // 8192
    int xcd = blk & 7, j = blk >> 3;            // j: 0..1023
    int b = 2 * xcd + (j >> 9);
    size_t row = (size_t)b * 2048 + (size_t)(j & 511) * 4 + w;
    float w0 = ml[row], w1 = ml[BM_ + row];
    float rs = 1.0f / (w0 + w1);
    float a0 = w0 * rs, a1 = w1 * rs;
    float4 v;
    ushort4 p1 = *reinterpret_cast<const ushort4*>(part1 + row * 256 + lane * 4);
    if (h0bf16) {
        ushort4 p0 = *reinterpret_cast<const ushort4*>(part0 + row * 256 + lane * 4);
        v.x = a0 * bf2f(p0.x) + a1 * bf2f(p1.x);
        v.y = a0 * bf2f(p0.y) + a1 * bf2f(p1.y);
        v.z = a0 * bf2f(p0.z) + a1 * bf2f(p1.z);
        v.w = a0 * bf2f(p0.w) + a1 * bf2f(p1.w);
    } else {
        float4 o0 = *reinterpret_cast<float4*>(out + row * 256 + lane * 4);
        v.x = a0 * o0.x + a1 * bf2f(p1.x);
        v.y = a0 * o0.y + a1 * bf2f(p1.y);
        v.z = a0 * o0.z + a1 * bf2f(p1.z);
        v.w = a0 * o0.w + a1 * bf2f(p1.w);
    }
    float s = v.x + v.y + v.z + v.w;
    float q = v.x * v.x + v.y * v.y + v.z * v.z + v.w * v.w;
    #pragma unroll
    for (int m = 1; m < 64; m <<= 1) { s += __shfl_xor(s, m); q += __shfl_xor(q, m); }
    float mu = s * (1.0f / 256.0f);
    float var = q * (1.0f / 256.0f) - mu * mu;
    float rstd = rsqrtf(var + 1e-5f);
    float4 gg = *reinterpret_cast<const float4*>(gam + lane * 4);
    float4 bb = *reinterpret_cast<const float4*>(bet + lane * 4);
    float4 o;
    o.x = (v.x - mu) * rstd * gg.x + bb.x;
    o.y = (v.y - mu) * rstd * gg.y + bb.y;
    o.z = (v.z - mu) * rstd * gg.z + bb.z;
    o.w = (v.w - mu) * rstd * gg.w + bb.w;
    o.x = o.x >= 0.f ? o.x : 0.01f * o.x;
    o.y = o.y >= 0.f ? o.y : 0.01f * o.y;
    o.z = o.z >= 0.f ? o.z : 0.01f * o.z;
    o.w = o.w >= 0.f ? o.w : 0.01f * o.w;
    *reinterpret_cast<float4*>(out + row * 256 + lane * 4) = o;
}

// ---------------------------------------------------------------- launcher
extern "C" void kernel_launch(void* const* d_in, const int* in_sizes, int n_in,
                              void* d_out, int out_size, void* d_ws, size_t ws_size,
                              hipStream_t stream) {
    const float* local_feat = (const float*)d_in[0];
    const float* adj_w    = (const float*)d_in[3];
    const float* affine_w = (const float*)d_in[4];
    const float* affine_b = (const float*)d_in[5];
    const float* ln_g     = (const float*)d_in[6];
    const float* ln_b     = (const float*)d_in[7];
    float* out = (float*)d_out;

    char* ws = (char*)d_ws;
    unsigned short* nf    = (unsigned short*)(ws);                 // 16 MiB (dead after dual_gemm)
    unsigned short* q     = (unsigned short*)(ws + 16777216);      // 16 MiB
    unsigned short* v3    = (unsigned short*)(ws + 33554432);      // 16 MiB
    unsigned short* k3    = (unsigned short*)(ws + 50331648);      // 16 MiB -> 67108864
    unsigned short* part0 = (unsigned short*)(ws);                 // aliases nf (dead)
    unsigned short* part1;
    unsigned short* adjT5;
    unsigned short* affw;
    float*          norms;
    float*          ml;

    // primary layout high-water = 84,279,296 B (r12 proved >= 84,283,392 B)
    const size_t need = 84279296ull;
    int h0bf16 = (ws_size >= need) ? 1 : 0;
    if (h0bf16) {
        part1 = (unsigned short*)(ws + 67108864);  // 16 MiB -> 83886080
        adjT5 = (unsigned short*)(ws + 83886080);  // 128 KiB
        affw  = (unsigned short*)(ws + 84017152);  // 128 KiB
        norms = (float*)         (ws + 84148224);  // 128 KiB -> 84279296
        ml    = (float*)         (ws + 83886080);  // aliases adjT5+affw (dead)
    } else {
        part1 = (unsigned short*)(ws);             // aliases nf (part0 unused)
        adjT5 = (unsigned short*)(ws + 67108864);  // 128 KiB
        affw  = (unsigned short*)(ws + 67239936);  // 128 KiB
        norms = (float*)         (ws + 67371008);  // 128 KiB -> 67502080 (r9-proven)
        ml    = (float*)         (ws + 67108864);  // aliases adjT5+affw (dead)
    }

    l2norm_prep_kernel<<<8448, 256, 0, stream>>>(local_feat, nf, norms,
                                                 adj_w, affine_w, adjT5, affw);
    dual_gemm<<<BM_ / 128, 512, 0, stream>>>(nf, adjT5, affw, norms, affine_b, q, v3, k3);
    flash_kernel<<<512, 256, 0, stream>>>(q, k3, v3, out, part0, part1, ml, h0bf16);
    merge_ln_kernel<<<8192, 256, 0, stream>>>(part0, part1, ml, ln_g, ln_b, out, h0bf16);
}